// Round 6
// baseline (230.392 us; speedup 1.0000x reference)
//
#include <hip/hip_runtime.h>
#include <math.h>

#define IND   64
#define OUTD  101
#define RPB   64
#define NCT   7          // 7 col-tiles x 16 = 112 padded cols

typedef _Float16 half8 __attribute__((ext_vector_type(8)));
typedef float    f32x4 __attribute__((ext_vector_type(4)));

__global__ __launch_bounds__(64, 4) void density_kernel(
    const float* __restrict__ t,
    const float* __restrict__ x,
    const float* __restrict__ weight,
    const float* __restrict__ bias,
    const int*   __restrict__ num_grid,
    float* __restrict__ out1,
    float* __restrict__ out_interp,
    int n_rows)
{
    __shared__ alignas(16) int liui[RPB];   // per-row packed (Li | Ui<<16)
    __shared__ float accL[RPB];             // per-row p[Li] (exactly 1 writer)
    __shared__ float accU[RPB];             // per-row p[Ui]

    const int lane = threadIdx.x;
    const int lc   = lane & 15;        // col-in-tile / row-in-rowtile
    const int lg   = lane >> 4;        // k-group / row-group
    const int row0 = blockIdx.x * RPB;

    // ---- B fragments (weights) + bias: 63 VGPR, loaded ONCE per block ----
    half8 bf[NCT][2];
    float biasv[NCT];
#pragma unroll
    for (int ct = 0; ct < NCT; ++ct) {
        const int col  = ct * 16 + lc;
        const int colc = (col < OUTD) ? col : (OUTD - 1);
        biasv[ct] = (col < OUTD) ? bias[col] : -1e30f;   // pad cols killed via bias
#pragma unroll
        for (int kg = 0; kg < 2; ++kg) {
            half8 h;
#pragma unroll
            for (int j = 0; j < 8; ++j)
                h[j] = (_Float16)weight[(kg * 32 + lg * 8 + j) * OUTD + colc];
            bf[ct][kg] = h;
        }
    }

    // ---- own-row interp indices -> LDS broadcast ----
    const float ngf = (float)num_grid[0];
    const int gr_i  = row0 + lane;
    const int grc_i = (gr_i < n_rows) ? gr_i : (n_rows - 1);
    const float tB  = t[grc_i] * ngf;
    const float Uf  = ceilf(tB);
    const float inter = 1.0f - (Uf - tB);   // stays in a register to the end
    float Lf = Uf - 1.0f;
    if (Lf < 0.0f) Lf += 1.0f;
    liui[lane] = ((int)Lf) | (((int)Uf) << 16);
    __syncthreads();

    // ---- 4 row-tiles of 16 rows ----
#pragma unroll 1
    for (int rt = 0; rt < 4; ++rt) {
        // A fragments: a[j] = x[row = rt*16+lc][k = kg*32 + lg*8 + j]
        const int grow  = row0 + rt * 16 + lc;
        const int growc = (grow < n_rows) ? grow : (n_rows - 1);
        const float* xr = x + (size_t)growc * IND + lg * 8;
        const f32x4 x0 = *(const f32x4*)(xr);
        const f32x4 x1 = *(const f32x4*)(xr + 4);
        const f32x4 x2 = *(const f32x4*)(xr + 32);
        const f32x4 x3 = *(const f32x4*)(xr + 36);
        half8 a0, a1;
#pragma unroll
        for (int i = 0; i < 4; ++i) {
            a0[i] = (_Float16)x0[i]; a0[4 + i] = (_Float16)x1[i];
            a1[i] = (_Float16)x2[i]; a1[4 + i] = (_Float16)x3[i];
        }

        // C = bias + x @ W  (K=64 via two MFMAs per col-tile)
        f32x4 c[NCT];
#pragma unroll
        for (int ct = 0; ct < NCT; ++ct) {
            f32x4 ci = {biasv[ct], biasv[ct], biasv[ct], biasv[ct]};
            ci = __builtin_amdgcn_mfma_f32_16x16x32_f16(a0, bf[ct][0], ci, 0, 0, 0);
            ci = __builtin_amdgcn_mfma_f32_16x16x32_f16(a1, bf[ct][1], ci, 0, 0, 0);
            c[ct] = ci;
        }

        // row-wise softmax: row = rt*16 + lg*4 + j; cols spread over 16 lanes
        float m[4], s[4];
#pragma unroll
        for (int j = 0; j < 4; ++j) {
            float mj = c[0][j];
#pragma unroll
            for (int ct = 1; ct < NCT; ++ct) mj = fmaxf(mj, c[ct][j]);
#pragma unroll
            for (int d = 1; d < 16; d <<= 1) mj = fmaxf(mj, __shfl_xor(mj, d, 64));
            m[j] = mj;
            s[j] = 0.0f;
        }
#pragma unroll
        for (int ct = 0; ct < NCT; ++ct)
#pragma unroll
            for (int j = 0; j < 4; ++j) {
                const float e = __expf(c[ct][j] - m[j]);
                c[ct][j] = e;
                s[j] += e;
            }
#pragma unroll
        for (int j = 0; j < 4; ++j) {
#pragma unroll
            for (int d = 1; d < 16; d <<= 1) s[j] += __shfl_xor(s[j], d, 64);
            float inv = __builtin_amdgcn_rcpf(s[j]);
            inv = inv * (2.0f - s[j] * inv);
            s[j] = inv;
        }
#pragma unroll
        for (int ct = 0; ct < NCT; ++ct)
#pragma unroll
            for (int j = 0; j < 4; ++j) c[ct][j] *= s[j];

        // direct out1 stores: 64B segments per 16-lane group, L2 merges
        const int rbase = row0 + rt * 16 + lg * 4;
#pragma unroll
        for (int ct = 0; ct < NCT; ++ct) {
            const int col = ct * 16 + lc;
            if (col < OUTD) {
#pragma unroll
                for (int j = 0; j < 4; ++j) {
                    const int r = rbase + j;
                    if (r < n_rows) out1[(size_t)r * OUTD + col] = c[ct][j];
                }
            }
        }

        // interp contributions: the single lane owning (row, col==Li/Ui)
        // writes the fp32 prob into the row's slot (exactly one writer).
        const int rl = rt * 16 + lg * 4;
        int lup[4];
        *(int4*)lup = *(const int4*)&liui[rl];   // 16B-aligned ds_read_b128
#pragma unroll
        for (int j = 0; j < 4; ++j) {
            const int LiR = lup[j] & 0xffff;
            const int UiR = lup[j] >> 16;
            const int ctL = LiR >> 4, lcL = LiR & 15;
            const int ctU = UiR >> 4, lcU = UiR & 15;
            float pL = 0.0f, pU = 0.0f;
#pragma unroll
            for (int ct = 0; ct < NCT; ++ct) {
                pL = (ct == ctL) ? c[ct][j] : pL;
                pU = (ct == ctU) ? c[ct][j] : pU;
            }
            if (lc == lcL) accL[rl + j] = pL;
            if (lc == lcU) accU[rl + j] = pU;
        }
    }

    __syncthreads();

    // ---- interp: lane = row, fp32 lerp ----
    if (gr_i < n_rows) {
        const float Lv = accL[lane];
        const float Uv = accU[lane];
        out_interp[gr_i] = Lv + (Uv - Lv) * inter;
    }
}

extern "C" void kernel_launch(void* const* d_in, const int* in_sizes, int n_in,
                              void* d_out, int out_size, void* d_ws, size_t ws_size,
                              hipStream_t stream) {
    const float* t  = (const float*)d_in[0];
    const float* x  = (const float*)d_in[1];
    const float* w  = (const float*)d_in[2];
    const float* b  = (const float*)d_in[3];
    const int*   ng = (const int*)d_in[4];
    const int n_rows = in_sizes[0];

    float* out1       = (float*)d_out;
    float* out_interp = out1 + (size_t)n_rows * OUTD;

    const int n_blocks = (n_rows + RPB - 1) / RPB;   // 15625
    density_kernel<<<dim3(n_blocks), dim3(64), 0, stream>>>(
        t, x, w, b, ng, out1, out_interp, n_rows);
}

// Round 7
// 209.669 us; speedup vs baseline: 1.0988x; 1.0988x over previous
//
#include <hip/hip_runtime.h>
#include <math.h>

#define IND      64
#define OUTD     101
#define RPB      256      // rows per block = 4 waves x 64
#define NCT      7        // 7 col-tiles x 16 = 112 padded cols
#define NCOL_PAD 112

typedef _Float16 half8 __attribute__((ext_vector_type(8)));
typedef float    f32x4 __attribute__((ext_vector_type(4)));

__global__ __launch_bounds__(256, 4) void density_kernel(
    const float* __restrict__ t,
    const float* __restrict__ x,
    const float* __restrict__ weight,
    const float* __restrict__ bias,
    const int*   __restrict__ num_grid,
    float* __restrict__ out1,
    float* __restrict__ out_interp,
    int n_rows)
{
    // W as fp16, [col][k] with 16B-slot XOR swizzle: slot_phys = kb ^ (col&7)
    __shared__ _Float16 wlds[NCOL_PAD * IND];   // 14336 B
    __shared__ alignas(16) int liui[RPB];       // per-row packed (Li | Ui<<16)
    __shared__ float accL[RPB];                 // per-row p[Li]
    __shared__ float accU[RPB];                 // per-row p[Ui]

    const int tid  = threadIdx.x;
    const int lane = tid & 63;
    const int wid  = tid >> 6;         // wave 0..3
    const int lc   = lane & 15;        // col-in-tile / row-in-rowtile
    const int lg   = lane >> 4;        // k-group / row-group
    const int row0 = blockIdx.x * RPB;

    // ---- stage W -> LDS fp16 (once per 256 rows) ----
    {
        const int c    = tid >> 1;     // 0..127
        const int khal = tid & 1;      // k half: 0 -> k 0..31, 1 -> k 32..63
        if (c < NCOL_PAD) {
            const int cc = (c < OUTD) ? c : (OUTD - 1);   // pads killed via bias
#pragma unroll
            for (int i = 0; i < 4; ++i) {
                const int kb = khal * 4 + i;   // logical 16B slot (8 k's)
                half8 h;
#pragma unroll
                for (int j = 0; j < 8; ++j)
                    h[j] = (_Float16)weight[(kb * 8 + j) * OUTD + cc];
                const int slot = kb ^ (c & 7);
                *(half8*)&wlds[c * IND + slot * 8] = h;
            }
        }
    }

    // ---- own-row interp indices -> LDS broadcast ----
    const float ngf = (float)num_grid[0];
    const int gr_i  = row0 + tid;
    const int grc_i = (gr_i < n_rows) ? gr_i : (n_rows - 1);
    const float tB  = t[grc_i] * ngf;
    const float Uf  = ceilf(tB);
    const float inter = 1.0f - (Uf - tB);       // stays in a register
    float Lf = Uf - 1.0f;
    if (Lf < 0.0f) Lf += 1.0f;
    liui[tid] = ((int)Lf) | (((int)Uf) << 16);

    // bias per lane (7 regs); pad cols get -1e30 so exp() -> 0
    float biasv[NCT];
#pragma unroll
    for (int ct = 0; ct < NCT; ++ct) {
        const int col = ct * 16 + lc;
        biasv[ct] = (col < OUTD) ? bias[col] : -1e30f;
    }

    __syncthreads();

    const int wrow0 = row0 + wid * 64;          // this wave's 64 rows

    // ---- 4 row-tiles of 16 rows per wave ----
#pragma unroll 1
    for (int rt = 0; rt < 4; ++rt) {
        // A fragments: a[j] = x[row = rt*16+lc][k = kg*32 + lg*8 + j]
        const int grow  = wrow0 + rt * 16 + lc;
        const int growc = (grow < n_rows) ? grow : (n_rows - 1);
        const float* xr = x + (size_t)growc * IND + lg * 8;
        const f32x4 x0 = *(const f32x4*)(xr);
        const f32x4 x1 = *(const f32x4*)(xr + 4);
        const f32x4 x2 = *(const f32x4*)(xr + 32);
        const f32x4 x3 = *(const f32x4*)(xr + 36);
        half8 a0, a1;
#pragma unroll
        for (int i = 0; i < 4; ++i) {
            a0[i] = (_Float16)x0[i]; a0[4 + i] = (_Float16)x1[i];
            a1[i] = (_Float16)x2[i]; a1[4 + i] = (_Float16)x3[i];
        }

        // C = bias + x @ W ; B fragments streamed from swizzled LDS
        f32x4 c[NCT];
#pragma unroll
        for (int ct = 0; ct < NCT; ++ct) {
            const int col   = ct * 16 + lc;
            const int slot0 = (lg)     ^ (col & 7);   // kg=0: kb = lg
            const int slot1 = (4 + lg) ^ (col & 7);   // kg=1: kb = 4+lg
            const half8 b0 = *(const half8*)&wlds[col * IND + slot0 * 8];
            const half8 b1 = *(const half8*)&wlds[col * IND + slot1 * 8];
            f32x4 ci = {biasv[ct], biasv[ct], biasv[ct], biasv[ct]};
            ci = __builtin_amdgcn_mfma_f32_16x16x32_f16(a0, b0, ci, 0, 0, 0);
            ci = __builtin_amdgcn_mfma_f32_16x16x32_f16(a1, b1, ci, 0, 0, 0);
            c[ct] = ci;
        }

        // row-wise softmax: row = rt*16 + lg*4 + j; cols spread over 16 lanes
        float m[4], s[4];
#pragma unroll
        for (int j = 0; j < 4; ++j) {
            float mj = c[0][j];
#pragma unroll
            for (int ct = 1; ct < NCT; ++ct) mj = fmaxf(mj, c[ct][j]);
#pragma unroll
            for (int d = 1; d < 16; d <<= 1) mj = fmaxf(mj, __shfl_xor(mj, d, 64));
            m[j] = mj;
            s[j] = 0.0f;
        }
#pragma unroll
        for (int ct = 0; ct < NCT; ++ct)
#pragma unroll
            for (int j = 0; j < 4; ++j) {
                const float e = __expf(c[ct][j] - m[j]);
                c[ct][j] = e;
                s[j] += e;
            }
#pragma unroll
        for (int j = 0; j < 4; ++j) {
#pragma unroll
            for (int d = 1; d < 16; d <<= 1) s[j] += __shfl_xor(s[j], d, 64);
            float inv = __builtin_amdgcn_rcpf(s[j]);
            inv = inv * (2.0f - s[j] * inv);
            s[j] = inv;
        }
#pragma unroll
        for (int ct = 0; ct < NCT; ++ct)
#pragma unroll
            for (int j = 0; j < 4; ++j) c[ct][j] *= s[j];

        // direct out1 stores: 64B segments per 16-lane group, L2 merges rows
        const int rbase = wrow0 + rt * 16 + lg * 4;
#pragma unroll
        for (int ct = 0; ct < NCT; ++ct) {
            const int col = ct * 16 + lc;
            if (col < OUTD) {
#pragma unroll
                for (int j = 0; j < 4; ++j) {
                    const int r = rbase + j;
                    if (r < n_rows) out1[(size_t)r * OUTD + col] = c[ct][j];
                }
            }
        }

        // interp contributions: lane owning (row, col==Li/Ui) writes fp32 prob
        const int rl = wid * 64 + rt * 16 + lg * 4;   // block-local row base
        int lup[4];
        *(int4*)lup = *(const int4*)&liui[rl];        // 16B-aligned ds_read_b128
#pragma unroll
        for (int j = 0; j < 4; ++j) {
            const int LiR = lup[j] & 0xffff;
            const int UiR = lup[j] >> 16;
            const int ctL = LiR >> 4, lcL = LiR & 15;
            const int ctU = UiR >> 4, lcU = UiR & 15;
            float pL = 0.0f, pU = 0.0f;
#pragma unroll
            for (int ct = 0; ct < NCT; ++ct) {
                pL = (ct == ctL) ? c[ct][j] : pL;
                pU = (ct == ctU) ? c[ct][j] : pU;
            }
            if (lc == lcL) accL[rl + j] = pL;
            if (lc == lcU) accU[rl + j] = pU;
        }
    }

    __syncthreads();

    // ---- interp: thread = row, fp32 lerp ----
    if (gr_i < n_rows) {
        const float Lv = accL[tid];
        const float Uv = accU[tid];
        out_interp[gr_i] = Lv + (Uv - Lv) * inter;
    }
}

extern "C" void kernel_launch(void* const* d_in, const int* in_sizes, int n_in,
                              void* d_out, int out_size, void* d_ws, size_t ws_size,
                              hipStream_t stream) {
    const float* t  = (const float*)d_in[0];
    const float* x  = (const float*)d_in[1];
    const float* w  = (const float*)d_in[2];
    const float* b  = (const float*)d_in[3];
    const int*   ng = (const int*)d_in[4];
    const int n_rows = in_sizes[0];

    float* out1       = (float*)d_out;
    float* out_interp = out1 + (size_t)n_rows * OUTD;

    const int n_blocks = (n_rows + RPB - 1) / RPB;   // 3907
    density_kernel<<<dim3(n_blocks), dim3(256), 0, stream>>>(
        t, x, w, b, ng, out1, out_interp, n_rows);
}

// Round 8
// 197.109 us; speedup vs baseline: 1.1689x; 1.0637x over previous
//
#include <hip/hip_runtime.h>
#include <math.h>

#define IND   64
#define OUTD  101
#define RPB   64
#define NCT   7          // 7 col-tiles x 16 = 112 padded cols

typedef _Float16 half8  __attribute__((ext_vector_type(8)));
typedef float    f32x4  __attribute__((ext_vector_type(4)));
typedef f32x4 __attribute__((aligned(4))) f32x4u;   // rows stride 101 floats -> 4B align

__global__ __launch_bounds__(64, 3) void density_kernel(
    const float* __restrict__ t,
    const float* __restrict__ x,
    const float* __restrict__ weight,
    const float* __restrict__ bias,
    const int*   __restrict__ num_grid,
    float* __restrict__ out1,
    float* __restrict__ out_interp,
    int n_rows)
{
    __shared__ alignas(16) float blds[NCT * 16];   // padded bias, 448 B
    __shared__ alignas(16) int   liui[RPB];        // per-row packed (Li | Ui<<16)
    __shared__ float accL[RPB];                    // per-row p[Li]
    __shared__ float accU[RPB];                    // per-row p[Ui]

    const int lane = threadIdx.x;
    const int lc   = lane & 15;        // row-in-rowtile (after operand swap)
    const int lg   = lane >> 4;        // k-group / col-quad group
    const int row0 = blockIdx.x * RPB;

    // ---- W fragments: 56 VGPR, loaded ONCE per block (contents = R5's) ----
    // wf[ct][kg][j] = W[k = kg*32 + lg*8 + j][col = ct*16 + lc]
    half8 wf[NCT][2];
#pragma unroll
    for (int ct = 0; ct < NCT; ++ct) {
        const int col  = ct * 16 + lc;
        const int colc = (col < OUTD) ? col : (OUTD - 1);  // pads killed via bias
#pragma unroll
        for (int kg = 0; kg < 2; ++kg) {
            half8 h;
#pragma unroll
            for (int j = 0; j < 8; ++j)
                h[j] = (_Float16)weight[(kg * 32 + lg * 8 + j) * OUTD + colc];
            wf[ct][kg] = h;
        }
    }

    // ---- bias -> LDS (padded with -1e30 so exp() of pad cols -> 0) ----
#pragma unroll
    for (int i = lane; i < NCT * 16; i += 64)
        blds[i] = (i < OUTD) ? bias[i] : -1e30f;

    // ---- own-row interp indices -> LDS broadcast ----
    const float ngf = (float)num_grid[0];
    const int gr_i  = row0 + lane;
    const int grc_i = (gr_i < n_rows) ? gr_i : (n_rows - 1);
    const float tB  = t[grc_i] * ngf;
    const float Uf  = ceilf(tB);
    const float inter = 1.0f - (Uf - tB);
    float Lf = Uf - 1.0f;
    if (Lf < 0.0f) Lf += 1.0f;
    liui[lane] = ((int)Lf) | (((int)Uf) << 16);
    __syncthreads();

    // ---- 4 row-tiles of 16 rows ----
#pragma unroll
    for (int rt = 0; rt < 4; ++rt) {
        // x fragments: xf[j] = x[row = rt*16+lc][k = kg*32 + lg*8 + j]
        const int grow  = row0 + rt * 16 + lc;
        const int growc = (grow < n_rows) ? grow : (n_rows - 1);
        const float* xr = x + (size_t)growc * IND + lg * 8;
        const f32x4 x0 = *(const f32x4*)(xr);
        const f32x4 x1 = *(const f32x4*)(xr + 4);
        const f32x4 x2 = *(const f32x4*)(xr + 32);
        const f32x4 x3 = *(const f32x4*)(xr + 36);
        half8 a0, a1;
#pragma unroll
        for (int i = 0; i < 4; ++i) {
            a0[i] = (_Float16)x0[i]; a0[4 + i] = (_Float16)x1[i];
            a1[i] = (_Float16)x2[i]; a1[4 + i] = (_Float16)x3[i];
        }

        // C^T = bias + (x @ W)^T : mfma(W, x) -> lane = row, regs = 4 cols
        // D layout: row = lane&15, col = ct*16 + (lane>>4)*4 + j
        f32x4 c[NCT];
#pragma unroll
        for (int ct = 0; ct < NCT; ++ct) {
            f32x4 ci = *(const f32x4*)&blds[ct * 16 + lg * 4];
            ci = __builtin_amdgcn_mfma_f32_16x16x32_f16(wf[ct][0], a0, ci, 0, 0, 0);
            ci = __builtin_amdgcn_mfma_f32_16x16x32_f16(wf[ct][1], a1, ci, 0, 0, 0);
            c[ct] = ci;
        }

        // softmax over the row: 28 regs in-lane + 2 shuffle steps (lg groups)
        float m = c[0][0];
#pragma unroll
        for (int ct = 0; ct < NCT; ++ct)
#pragma unroll
            for (int j = 0; j < 4; ++j) m = fmaxf(m, c[ct][j]);
        m = fmaxf(m, __shfl_xor(m, 16, 64));
        m = fmaxf(m, __shfl_xor(m, 32, 64));

        float s = 0.0f;
#pragma unroll
        for (int ct = 0; ct < NCT; ++ct)
#pragma unroll
            for (int j = 0; j < 4; ++j) {
                const float e = __expf(c[ct][j] - m);
                c[ct][j] = e;
                s += e;
            }
        s += __shfl_xor(s, 16, 64);
        s += __shfl_xor(s, 32, 64);
        float inv = __builtin_amdgcn_rcpf(s);
        inv = inv * (2.0f - s * inv);
#pragma unroll
        for (int ct = 0; ct < NCT; ++ct)
#pragma unroll
            for (int j = 0; j < 4; ++j) c[ct][j] *= inv;

        // vectorized stores: dwordx4, 16 rows x 64B contiguous per instr
        float* orow = out1 + (size_t)grow * OUTD;
#pragma unroll
        for (int ct = 0; ct < 6; ++ct)
            *(f32x4u*)&orow[ct * 16 + lg * 4] = c[ct];
        if (lg == 0) *(f32x4u*)&orow[96] = c[6];        // cols 96..99
        if (lg == 1) orow[100] = c[6][0];               // col 100

        // interp contribution: owner lane (lg == Li>>2 & 3) writes fp32 prob
        const int rl = rt * 16 + lc;                    // block-local row
        const int lu = liui[rl];
        const int Li = lu & 0xffff;
        const int Ui = lu >> 16;
        float pL = 0.0f, pU = 0.0f;
#pragma unroll
        for (int ct = 0; ct < NCT; ++ct) {
#pragma unroll
            for (int j = 0; j < 4; ++j) {
                const int colLj = ct * 16 + ((Li >> 2) & 3) * 4 + j;
                const int colUj = ct * 16 + ((Ui >> 2) & 3) * 4 + j;
                pL = (colLj == Li) ? c[ct][j] : pL;
                pU = (colUj == Ui) ? c[ct][j] : pU;
            }
        }
        if (lg == ((Li >> 2) & 3)) accL[rl] = pL;
        if (lg == ((Ui >> 2) & 3)) accU[rl] = pU;
    }

    __syncthreads();

    // ---- interp: lane = row, fp32 lerp ----
    if (gr_i < n_rows) {
        const float Lv = accL[lane];
        const float Uv = accU[lane];
        out_interp[gr_i] = Lv + (Uv - Lv) * inter;
    }
}

extern "C" void kernel_launch(void* const* d_in, const int* in_sizes, int n_in,
                              void* d_out, int out_size, void* d_ws, size_t ws_size,
                              hipStream_t stream) {
    const float* t  = (const float*)d_in[0];
    const float* x  = (const float*)d_in[1];
    const float* w  = (const float*)d_in[2];
    const float* b  = (const float*)d_in[3];
    const int*   ng = (const int*)d_in[4];
    const int n_rows = in_sizes[0];

    float* out1       = (float*)d_out;
    float* out_interp = out1 + (size_t)n_rows * OUTD;

    const int n_blocks = (n_rows + RPB - 1) / RPB;   // 15625 (exact, no tail)
    density_kernel<<<dim3(n_blocks), dim3(64), 0, stream>>>(
        t, x, w, b, ng, out1, out_interp, n_rows);
}

// Round 9
// 170.190 us; speedup vs baseline: 1.3537x; 1.1582x over previous
//
#include <hip/hip_runtime.h>
#include <math.h>

#define IND   64
#define OUTD  101
#define RPB   64
#define NCT   7          // 7 col-tiles x 16 = 112 padded cols

typedef _Float16 half8 __attribute__((ext_vector_type(8)));
typedef float    f32x4 __attribute__((ext_vector_type(4)));

__global__ __launch_bounds__(64, 3) void density_kernel(
    const float* __restrict__ t,
    const float* __restrict__ x,
    const float* __restrict__ weight,
    const float* __restrict__ bias,
    const int*   __restrict__ num_grid,
    float* __restrict__ out1,
    float* __restrict__ out_interp,
    int n_rows, int n_tiles, int n_blocks)
{
    __shared__ alignas(16) int liui[RPB];   // per-row packed (Li | Ui<<16)
    __shared__ float accL[RPB];             // per-row p[Li]
    __shared__ float accU[RPB];             // per-row p[Ui]

    const int lane = threadIdx.x;
    const int lc   = lane & 15;        // col-in-tile (R5 mapping)
    const int lg   = lane >> 4;        // k-group / row-group
    const float ngf = (float)num_grid[0];

    // ---- W fragments + bias: 63 VGPR, loaded ONCE per persistent block ----
    // wf[ct][kg][j] = W[k = kg*32 + lg*8 + j][col = ct*16 + lc]
    half8 wf[NCT][2];
    float biasv[NCT];
#pragma unroll
    for (int ct = 0; ct < NCT; ++ct) {
        const int col  = ct * 16 + lc;
        const int colc = (col < OUTD) ? col : (OUTD - 1);
        biasv[ct] = (col < OUTD) ? bias[col] : -1e30f;   // pads killed via bias
#pragma unroll
        for (int kg = 0; kg < 2; ++kg) {
            half8 h;
#pragma unroll
            for (int j = 0; j < 8; ++j)
                h[j] = (_Float16)weight[(kg * 32 + lg * 8 + j) * OUTD + colc];
            wf[ct][kg] = h;
        }
    }

    // x-row address for (tile, rt); lane lc picks the row, lg picks k-offset
    #define XPTR(TILE, RT) \
        ((const f32x4*)(x + (size_t)min((TILE) * RPB + (RT) * 16 + lc, n_rows - 1) * IND + lg * 8))

    // ---- 2-deep ping-pong x prefetch (static register names, rule #20) ----
    f32x4 pa0, pa1, pa2, pa3, pb0, pb1, pb2, pb3;

    int tile = blockIdx.x;
    {   // prime: tile rt=0 -> A buffer
        const f32x4* p = XPTR(tile, 0);
        pa0 = p[0]; pa1 = p[1]; pa2 = p[8]; pa3 = p[9];
    }

    // one row-tile: consume CUR regs, prefetch (PT,PR) into NXT regs
    #define PROCESS(RT, C0, C1, C2, C3, N0, N1, N2, N3, PT, PR)                  \
    {                                                                            \
        {   const f32x4* np = XPTR(PT, PR);                                      \
            N0 = np[0]; N1 = np[1]; N2 = np[8]; N3 = np[9]; }                    \
        half8 a0, a1;                                                            \
        _Pragma("unroll")                                                        \
        for (int i = 0; i < 4; ++i) {                                            \
            a0[i] = (_Float16)C0[i]; a0[4 + i] = (_Float16)C1[i];                \
            a1[i] = (_Float16)C2[i]; a1[4 + i] = (_Float16)C3[i];                \
        }                                                                        \
        f32x4 c[NCT];                                                            \
        _Pragma("unroll")                                                        \
        for (int ct = 0; ct < NCT; ++ct) {                                       \
            f32x4 ci = {biasv[ct], biasv[ct], biasv[ct], biasv[ct]};             \
            ci = __builtin_amdgcn_mfma_f32_16x16x32_f16(a0, wf[ct][0], ci,0,0,0);\
            ci = __builtin_amdgcn_mfma_f32_16x16x32_f16(a1, wf[ct][1], ci,0,0,0);\
            c[ct] = ci;                                                          \
        }                                                                        \
        float m[4], s[4];                                                        \
        _Pragma("unroll")                                                        \
        for (int j = 0; j < 4; ++j) {                                            \
            float mj = c[0][j];                                                  \
            _Pragma("unroll")                                                    \
            for (int ct = 1; ct < NCT; ++ct) mj = fmaxf(mj, c[ct][j]);           \
            _Pragma("unroll")                                                    \
            for (int d = 1; d < 16; d <<= 1) mj = fmaxf(mj, __shfl_xor(mj,d,64));\
            m[j] = mj; s[j] = 0.0f;                                              \
        }                                                                        \
        _Pragma("unroll")                                                        \
        for (int ct = 0; ct < NCT; ++ct)                                         \
            _Pragma("unroll")                                                    \
            for (int j = 0; j < 4; ++j) {                                        \
                const float e = __expf(c[ct][j] - m[j]);                         \
                c[ct][j] = e; s[j] += e;                                         \
            }                                                                    \
        _Pragma("unroll")                                                        \
        for (int j = 0; j < 4; ++j) {                                            \
            _Pragma("unroll")                                                    \
            for (int d = 1; d < 16; d <<= 1) s[j] += __shfl_xor(s[j], d, 64);    \
            float inv = __builtin_amdgcn_rcpf(s[j]);                             \
            inv = inv * (2.0f - s[j] * inv);                                     \
            s[j] = inv;                                                          \
        }                                                                        \
        _Pragma("unroll")                                                        \
        for (int ct = 0; ct < NCT; ++ct)                                         \
            _Pragma("unroll")                                                    \
            for (int j = 0; j < 4; ++j) c[ct][j] *= s[j];                        \
        const int rbase = row0 + RT * 16 + lg * 4;                               \
        _Pragma("unroll")                                                        \
        for (int j = 0; j < 4; ++j) {                                            \
            const int r = rbase + j;                                             \
            if (r < n_rows) {                                                    \
                float* orow = out1 + (size_t)r * OUTD;                           \
                _Pragma("unroll")                                                \
                for (int ct = 0; ct < NCT; ++ct) {                               \
                    const int col = ct * 16 + lc;                                \
                    if (col < OUTD) orow[col] = c[ct][j];                        \
                }                                                                \
            }                                                                    \
        }                                                                        \
        const int rl = RT * 16 + lg * 4;                                         \
        int lup[4];                                                              \
        *(int4*)lup = *(const int4*)&liui[rl];                                   \
        _Pragma("unroll")                                                        \
        for (int j = 0; j < 4; ++j) {                                            \
            const int LiR = lup[j] & 0xffff;                                     \
            const int UiR = lup[j] >> 16;                                        \
            const int ctL = LiR >> 4, lcL = LiR & 15;                            \
            const int ctU = UiR >> 4, lcU = UiR & 15;                            \
            float pL = 0.0f, pU = 0.0f;                                          \
            _Pragma("unroll")                                                    \
            for (int ct = 0; ct < NCT; ++ct) {                                   \
                pL = (ct == ctL) ? c[ct][j] : pL;                                \
                pU = (ct == ctU) ? c[ct][j] : pU;                                \
            }                                                                    \
            if (lc == lcL) accL[rl + j] = pL;                                    \
            if (lc == lcU) accU[rl + j] = pU;                                    \
        }                                                                        \
    }

    for (; tile < n_tiles; tile += n_blocks) {
        const int row0 = tile * RPB;

        // own-row interp indices -> LDS broadcast (1-wave block: cheap sync)
        const int gr  = row0 + lane;
        const int grc = (gr < n_rows) ? gr : (n_rows - 1);
        const float tB = t[grc] * ngf;
        const float Uf = ceilf(tB);
        const float inter = 1.0f - (Uf - tB);
        float Lf = Uf - 1.0f;
        if (Lf < 0.0f) Lf += 1.0f;
        liui[lane] = ((int)Lf) | (((int)Uf) << 16);
        __syncthreads();

        const int  ntile = tile + n_blocks;
        const int  pt    = (ntile < n_tiles) ? ntile : tile;   // clamp: dummy reload

        PROCESS(0, pa0, pa1, pa2, pa3, pb0, pb1, pb2, pb3, tile, 1)
        PROCESS(1, pb0, pb1, pb2, pb3, pa0, pa1, pa2, pa3, tile, 2)
        PROCESS(2, pa0, pa1, pa2, pa3, pb0, pb1, pb2, pb3, tile, 3)
        PROCESS(3, pb0, pb1, pb2, pb3, pa0, pa1, pa2, pa3, pt,   0)

        __syncthreads();

        // interp: lane = row, fp32 lerp
        if (gr < n_rows) {
            const float Lv = accL[lane];
            const float Uv = accU[lane];
            out_interp[gr] = Lv + (Uv - Lv) * inter;
        }
    }
    #undef PROCESS
    #undef XPTR
}

extern "C" void kernel_launch(void* const* d_in, const int* in_sizes, int n_in,
                              void* d_out, int out_size, void* d_ws, size_t ws_size,
                              hipStream_t stream) {
    const float* t  = (const float*)d_in[0];
    const float* x  = (const float*)d_in[1];
    const float* w  = (const float*)d_in[2];
    const float* b  = (const float*)d_in[3];
    const int*   ng = (const int*)d_in[4];
    const int n_rows = in_sizes[0];

    float* out1       = (float*)d_out;
    float* out_interp = out1 + (size_t)n_rows * OUTD;

    const int n_tiles  = (n_rows + RPB - 1) / RPB;   // 15625
    const int n_blocks = 3072;                       // 3 waves/SIMD x 1024 SIMDs
    density_kernel<<<dim3(n_blocks), dim3(64), 0, stream>>>(
        t, x, w, b, ng, out1, out_interp, n_rows, n_tiles, n_blocks);
}